// Round 3
// baseline (271.142 us; speedup 1.0000x reference)
//
#include <hip/hip_runtime.h>

#define E_EDGES 32768
#define NN 8192
#define HID 128
#define KS 4

typedef _Float16 half8 __attribute__((ext_vector_type(8)));
typedef _Float16 half4 __attribute__((ext_vector_type(4)));
typedef float f32x4 __attribute__((ext_vector_type(4)));

// ------- CSR build: zero + hist(LDS) + scan, one single-block kernel -------
__global__ void csr_scan_k(const int* __restrict__ dst, float* __restrict__ pools,
                           int npool, int* __restrict__ roff, int* __restrict__ cursor) {
  __shared__ int h[NN];      // 32 KB
  __shared__ int ps[1024];
  int t = threadIdx.x;       // 1024 threads
  for (int j = t; j < NN; j += 1024) h[j] = 0;
  for (int j = t; j < npool; j += 1024) pools[j] = 0.f;
  __syncthreads();
  for (int j = t; j < E_EDGES; j += 1024) atomicAdd(&h[dst[j]], 1);
  __syncthreads();
  int loc[8]; int s = 0;
  int base = t * 8;
#pragma unroll
  for (int j = 0; j < 8; ++j) { loc[j] = s; s += h[base + j]; }
  ps[t] = s;
  __syncthreads();
  for (int off = 1; off < 1024; off <<= 1) {
    int v = 0;
    if (t >= off) v = ps[t - off];
    __syncthreads();
    if (t >= off) ps[t] += v;
    __syncthreads();
  }
  int excl = (t == 0) ? 0 : ps[t - 1];
#pragma unroll
  for (int j = 0; j < 8; ++j) { int v = excl + loc[j]; roff[base + j] = v; cursor[base + j] = v; }
  if (t == 1023) roff[NN] = ps[1023];
}

__global__ void scatter_k(const int* __restrict__ dst, int* __restrict__ cursor, int* __restrict__ eidx) {
  int e = blockIdx.x * 256 + threadIdx.x;
  if (e < E_EDGES) { int p = atomicAdd(&cursor[dst[e]], 1); eidx[p] = e; }
}

// ------- W2 -> f16 B-matrix, MFMA-fragment-linear layout, all 3 layers -----
// k<128*CI theta rows (k=h*CI+i), next CI rows = b2 (he==1), zero to Kpad.
// out[((k>>3)*CO + n)*8 + (k&7)]: one lane's b-frag = contiguous 16B.
__device__ __forceinline__ void prep_one(int idx, int l2ci, int l2co,
                                         const float* __restrict__ W2,
                                         const float* __restrict__ b2,
                                         _Float16* __restrict__ out) {
  int CI = 1 << l2ci, CO = 1 << l2co;
  int Kmain = CI << 7;
  int j = idx & 7;
  int n = (idx >> 3) & (CO - 1);
  int kg = idx >> (3 + l2co);
  int k = kg * 8 + j;
  float v = 0.f;
  if (k < Kmain) {
    int hh = k >> l2ci, i = k & (CI - 1);
    v = W2[((hh << l2ci) + i) * CO + n];
  } else if (k < Kmain + CI) {
    v = b2[(k - Kmain) * CO + n];
  }
  out[idx] = (_Float16)v;
}

__global__ void prep_all_k(const float* __restrict__ W2a, const float* __restrict__ b2a, _Float16* __restrict__ oa,
                           const float* __restrict__ W2b, const float* __restrict__ b2b, _Float16* __restrict__ ob,
                           const float* __restrict__ W2c, const float* __restrict__ b2c, _Float16* __restrict__ oc) {
  const int s0 = 2176 * 32, s1 = 4224 * 64, s2 = 8320 * 64;
  int idx = blockIdx.x * 256 + threadIdx.x;
  if (idx < s0) prep_one(idx, 4, 5, W2a, b2a, oa);
  else if (idx < s0 + s1) prep_one(idx - s0, 5, 6, W2b, b2b, ob);
  else if (idx < s0 + s1 + s2) prep_one(idx - s0 - s1, 6, 6, W2c, b2c, oc);
}

// ------- main fused kernel: edge MLP1 + Z@W2r GEMM (split-K=4) -------------
// K-loop: A-fragments in REGISTERS (xreg, loop-invariant per lane), he via
// ds_read_u16 only, B-fragments streamed from global (L1/L2-resident) with
// depth-4 rotating register prefetch. No __syncthreads, no ds_read_b128.
template <int CI, int CO>
__launch_bounds__(256, 2)
__global__ void msg_mfma_k(const float* __restrict__ xcur, const int* __restrict__ src,
                           const float* __restrict__ eattr, const float* __restrict__ W1,
                           const float* __restrict__ b1, const _Float16* __restrict__ Bsw,
                           float* __restrict__ msgbuf) {
  constexpr int ME = 256;                      // edges per block
  constexpr int L2CI = (CI == 64) ? 6 : ((CI == 32) ? 5 : 4);
  constexpr int Kmain = 128 * CI;
  constexpr int SPLITK = 32 * CI;              // k per split (splits 0..2)
  constexpr int TAILK = ((SPLITK + CI + 127) / 128) * 128;
  constexpr int XSTR = CI + 8;
  constexpr int FC = CO / 16;
  constexpr int C4 = CI / 4;
  constexpr int L2C4 = L2CI - 2;
  constexpr int NV = (CI == 64) ? 2 : 1;       // x-fragment variants per lane

  __shared__ _Float16 he_s[32 * ME];           // [h-local(32)][e]
  __shared__ _Float16 xs_s[ME * XSTR];         // [e][i]
  __shared__ float ea_s[ME * 5];
  __shared__ float W1s[5 * 32];
  __shared__ float b1s[32];
  __shared__ int src_s[ME];

  int t = threadIdx.x;
  int e0 = blockIdx.x * ME;
  int y = blockIdx.y;                          // split: h in [32y, 32y+32)
  int hbeg = y * 32;

  for (int j = t; j < ME * 5; j += 256) ea_s[j] = eattr[e0 * 5 + j];
  if (t < 5 * 32) W1s[t] = W1[(t >> 5) * HID + hbeg + (t & 31)];
  if (t < 32) b1s[t] = b1[hbeg + t];
  src_s[t] = src[e0 + t];
  __syncthreads();

  for (int j = t; j < 32 * ME; j += 256) {
    int hl = j / ME, e = j & (ME - 1);
    float v = b1s[hl];
#pragma unroll
    for (int d = 0; d < 5; ++d) v += ea_s[e * 5 + d] * W1s[d * 32 + hl];
    he_s[hl * ME + e] = (_Float16)fmaxf(v, 0.f);
  }
  for (int j = t; j < ME * C4; j += 256) {
    int e = j >> L2C4, i4 = j & (C4 - 1);
    float4 v = ((const float4*)xcur)[src_s[e] * C4 + i4];
    half4 hq = {(_Float16)v.x, (_Float16)v.y, (_Float16)v.z, (_Float16)v.w};
    *(half4*)&xs_s[e * XSTR + i4 * 4] = hq;
  }
  __syncthreads();                             // last barrier

  int lane = t & 63;
  int w = t >> 6;
  int quad = lane >> 4, l15 = lane & 15;

  // loop-invariant per-lane A-side x fragments -> registers
  half8 xreg[4][NV];
#pragma unroll
  for (int fr = 0; fr < 4; ++fr)
#pragma unroll
    for (int v = 0; v < NV; ++v)
      xreg[fr][v] = *(const half8*)&xs_s[(w * 64 + fr * 16 + l15) * XSTR +
                                         ((quad * 8 + v * 32) & (CI - 1))];

  int cbeg = y * (SPLITK / 32);
  int cend = cbeg + ((y < 3) ? (SPLITK / 32) : (TAILK / 32));
  int nrounds = (cend - cbeg) >> 2;

  const half8* bsw8 = (const half8*)Bsw;
  int ib = quad * CO + l15;

  f32x4 acc[4][FC];
#pragma unroll
  for (int fr = 0; fr < 4; ++fr)
#pragma unroll
    for (int fc = 0; fc < FC; ++fc)
#pragma unroll
      for (int r = 0; r < 4; ++r) acc[fr][fc][r] = 0.f;

  half8 breg[4][FC];
#pragma unroll
  for (int j = 0; j < 4; ++j)
#pragma unroll
    for (int fc = 0; fc < FC; ++fc)
      breg[j][fc] = bsw8[(cbeg + j) * 4 * CO + ib + fc * 16];

  for (int r = 0; r < nrounds; ++r) {
#pragma unroll
    for (int j = 0; j < 4; ++j) {
      int c = cbeg + r * 4 + j;
      int kq = c * 32 + quad * 8;
      int hr = (kq >> L2CI) - hbeg;
      constexpr int PAR = (CI == 64) ? 1 : 0;  // chunk parity selects variant
      int vi = PAR ? (j & 1) : 0;              // cbeg even, r*4 even -> parity=j&1
      half8 a[4];
#pragma unroll
      for (int fr = 0; fr < 4; ++fr) {
        int e = w * 64 + fr * 16 + l15;
        _Float16 hv = (_Float16)1.f;
        if (kq < Kmain) hv = he_s[hr * ME + e];
        a[fr] = xreg[fr][vi] * hv;
      }
#pragma unroll
      for (int fc = 0; fc < FC; ++fc) {
#pragma unroll
        for (int fr = 0; fr < 4; ++fr)
          acc[fr][fc] = __builtin_amdgcn_mfma_f32_16x16x32_f16(a[fr], breg[j][fc], acc[fr][fc], 0, 0, 0);
      }
      int cn = c + 4;
      if (cn >= cend) cn = cend - 1;           // clamped branch-free prefetch
#pragma unroll
      for (int fc = 0; fc < FC; ++fc)
        breg[j][fc] = bsw8[cn * 4 * CO + ib + fc * 16];
    }
  }

  // epilogue: plain partial writes; C/D: row(e)=quad*4+r, col(o)=l15
  float* mb = msgbuf + ((size_t)y * E_EDGES + e0) * CO;
#pragma unroll
  for (int fr = 0; fr < 4; ++fr)
#pragma unroll
    for (int fc = 0; fc < FC; ++fc)
#pragma unroll
      for (int r = 0; r < 4; ++r) {
        int el = w * 64 + fr * 16 + quad * 4 + r;
        int o = fc * 16 + l15;
        mb[el * CO + o] = acc[fr][fc][r];
      }
}

// ------- scatter-sum via CSR gather + x@root + bias + ELU ------------------
template <int CI, int CO>
__global__ void gather_elu_k(const float* __restrict__ xcur, const float* __restrict__ root,
                             const float* __restrict__ bias, const float* __restrict__ msgbuf,
                             const int* __restrict__ roff, const int* __restrict__ eidx,
                             float* __restrict__ xnext) {
  constexpr int NB = 256 / CO;
  __shared__ float xs[NB * CI];
  int t = threadIdx.x;
  int n0 = blockIdx.x * NB;
  for (int j = t; j < NB * CI; j += 256) xs[j] = xcur[n0 * CI + j];
  __syncthreads();
  int nl = t / CO, o = t & (CO - 1);
  int n = n0 + nl;
  float a = bias[o];
#pragma unroll
  for (int i = 0; i < CI; ++i) a += xs[nl * CI + i] * root[i * CO + o];
  int j1 = roff[n + 1];
  for (int j = roff[n]; j < j1; ++j) {
    int e = eidx[j];
    float m = 0.f;
#pragma unroll
    for (int s = 0; s < KS; ++s) m += msgbuf[((size_t)s * E_EDGES + e) * CO + o];
    a += m;
  }
  xnext[n * CO + o] = a > 0.f ? a : expm1f(a);
}

// ------- pooling + MLP head ------------------------------------------------
__global__ void pool_sub_k(const float* __restrict__ x3, const int* __restrict__ n2s,
                           float* __restrict__ ssum, float* __restrict__ scnt) {
  int idx = blockIdx.x * 256 + threadIdx.x;  // over NN*64
  int n = idx >> 6, o = idx & 63;
  int s = n2s[n];
  atomicAdd(&ssum[(s << 6) + o], x3[idx]);
  if (o == 0) atomicAdd(&scnt[s], 1.f);
}

__global__ void pool_graph_k(const float* __restrict__ ssum, const float* __restrict__ scnt,
                             const int* __restrict__ s2g, float* __restrict__ gsum,
                             float* __restrict__ gcnt) {
  int idx = blockIdx.x * 256 + threadIdx.x;  // over 512*64
  int s = idx >> 6, o = idx & 63;
  int g = s2g[s];
  float v = ssum[idx] / fmaxf(scnt[s], 1.f);
  atomicAdd(&gsum[(g << 6) + o], v);
  if (o == 0) atomicAdd(&gcnt[g], 1.f);
}

__global__ void head_k(const float* __restrict__ gsum, const float* __restrict__ gcnt,
                       const float* __restrict__ w1, const float* __restrict__ b1,
                       const float* __restrict__ w2, const float* __restrict__ b2,
                       const float* __restrict__ w3, const float* __restrict__ b3,
                       float* __restrict__ out) {
  int g = blockIdx.x;
  int t = threadIdx.x;  // 64 threads
  __shared__ float m[64], s1[32], s2[16];
  float c = fmaxf(gcnt[g], 1.f);
  m[t] = gsum[g * 64 + t] / c;
  __syncthreads();
  if (t < 32) {
    float a = b1[t];
    for (int i = 0; i < 64; ++i) a += m[i] * w1[i * 32 + t];
    s1[t] = a > 0.f ? a : expm1f(a);
  }
  __syncthreads();
  if (t < 16) {
    float a = b2[t];
    for (int i = 0; i < 32; ++i) a += s1[i] * w2[i * 16 + t];
    s2[t] = a > 0.f ? a : expm1f(a);
  }
  __syncthreads();
  if (t == 0) {
    float a = b3[0];
    for (int i = 0; i < 16; ++i) a += s2[i] * w3[i];
    out[g] = a;
  }
}

extern "C" void kernel_launch(void* const* d_in, const int* in_sizes, int n_in,
                              void* d_out, int out_size, void* d_ws, size_t ws_size,
                              hipStream_t stream) {
  (void)in_sizes; (void)n_in; (void)out_size; (void)ws_size;
  const float* x0 = (const float*)d_in[0];
  const int* ei = (const int*)d_in[1];
  const float* ea = (const float*)d_in[2];
  const int* n2s = (const int*)d_in[3];
  const int* s2g = (const int*)d_in[4];
  const float* W1_[3] = {(const float*)d_in[5], (const float*)d_in[11], (const float*)d_in[17]};
  const float* b1_[3] = {(const float*)d_in[6], (const float*)d_in[12], (const float*)d_in[18]};
  const float* W2_[3] = {(const float*)d_in[7], (const float*)d_in[13], (const float*)d_in[19]};
  const float* b2_[3] = {(const float*)d_in[8], (const float*)d_in[14], (const float*)d_in[20]};
  const float* rt_[3] = {(const float*)d_in[9], (const float*)d_in[15], (const float*)d_in[21]};
  const float* bs_[3] = {(const float*)d_in[10], (const float*)d_in[16], (const float*)d_in[22]};
  const float* fc1w = (const float*)d_in[23]; const float* fc1b = (const float*)d_in[24];
  const float* fc2w = (const float*)d_in[25]; const float* fc2b = (const float*)d_in[26];
  const float* fc3w = (const float*)d_in[27]; const float* fc3b = (const float*)d_in[28];
  float* out = (float*)d_out;

  const int* srcp = ei;
  const int* dstp = ei + E_EDGES;

  char* wsb = (char*)d_ws;
  size_t off = 0;
  auto alloc = [&](size_t bytes) {
    void* p = wsb + off;
    off += (bytes + 255) & ~(size_t)255;
    return p;
  };
  // Kpad: L0(CI=16): 2176, L1(CI=32): 4224, L2(CI=64): 8320
  _Float16* Bsw0 = (_Float16*)alloc((size_t)2176 * 32 * 2);
  _Float16* Bsw1 = (_Float16*)alloc((size_t)4224 * 64 * 2);
  _Float16* Bsw2 = (_Float16*)alloc((size_t)8320 * 64 * 2);
  float* msgbuf = (float*)alloc((size_t)KS * E_EDGES * 64 * 4);
  float* x1 = (float*)alloc((size_t)NN * 32 * 4);
  float* x2 = (float*)alloc((size_t)NN * 64 * 4);
  float* x3 = (float*)alloc((size_t)NN * 64 * 4);
  int* roff = (int*)alloc((size_t)(NN + 1) * 4);
  int* cursor = (int*)alloc((size_t)NN * 4);
  int* eidx = (int*)alloc((size_t)E_EDGES * 4);
  const int npool = 512 * 64 + 512 + 32 * 64 + 32;
  float* pools = (float*)alloc((size_t)npool * 4);
  float* ssum = pools;
  float* scnt = pools + 512 * 64;
  float* gsum = scnt + 512;
  float* gcnt = gsum + 32 * 64;

  csr_scan_k<<<1, 1024, 0, stream>>>(dstp, pools, npool, roff, cursor);
  scatter_k<<<E_EDGES / 256, 256, 0, stream>>>(dstp, cursor, eidx);
  const int preptot = 2176 * 32 + 4224 * 64 + 8320 * 64;
  prep_all_k<<<(preptot + 255) / 256, 256, 0, stream>>>(W2_[0], b2_[0], Bsw0,
                                                        W2_[1], b2_[1], Bsw1,
                                                        W2_[2], b2_[2], Bsw2);

  dim3 mg(E_EDGES / 256, KS);
  msg_mfma_k<16, 32><<<mg, 256, 0, stream>>>(x0, srcp, ea, W1_[0], b1_[0], Bsw0, msgbuf);
  gather_elu_k<16, 32><<<NN / 8, 256, 0, stream>>>(x0, rt_[0], bs_[0], msgbuf, roff, eidx, x1);
  msg_mfma_k<32, 64><<<mg, 256, 0, stream>>>(x1, srcp, ea, W1_[1], b1_[1], Bsw1, msgbuf);
  gather_elu_k<32, 64><<<NN / 4, 256, 0, stream>>>(x1, rt_[1], bs_[1], msgbuf, roff, eidx, x2);
  msg_mfma_k<64, 64><<<mg, 256, 0, stream>>>(x2, srcp, ea, W1_[2], b1_[2], Bsw2, msgbuf);
  gather_elu_k<64, 64><<<NN / 4, 256, 0, stream>>>(x2, rt_[2], bs_[2], msgbuf, roff, eidx, x3);

  pool_sub_k<<<NN * 64 / 256, 256, 0, stream>>>(x3, n2s, ssum, scnt);
  pool_graph_k<<<512 * 64 / 256, 256, 0, stream>>>(ssum, scnt, s2g, gsum, gcnt);
  head_k<<<32, 64, 0, stream>>>(gsum, gcnt, fc1w, fc1b, fc2w, fc2b, fc3w, fc3b, out);
}